// Round 7
// baseline (307.436 us; speedup 1.0000x reference)
//
#include <hip/hip_runtime.h>
#include <math.h>

#define NSEG 7320
#define NLON 120
#define HIDN 128
#define ECH  16     // entries per k2 block (uniform -> perfect balance)
#define MAXCH 48    // 48*16 = 768-entry cap per row (max row ~520; R4/R6-proven)

// ---------------------------------------------------------------------------
// K1: grp 0-23: LN0 + QKV projection (8 output channels per group), planar
// [64][NSEG] outputs, coalesced. q pre-scaled by 1/sqrt(DH)=0.25.
// grp 24: meta {hi*120, dl, qw bits, ho} + per-lat-row CSR offsets.
// grp 25-26: zero num[64][NSEG]+den[4][NSEG] (contiguous, float4 stride loop).
// ---------------------------------------------------------------------------
__global__ __launch_bounds__(64) void k1_ln_qkv(
    const float* __restrict__ x,  const float* __restrict__ wq,
    const float* __restrict__ wk, const float* __restrict__ wv,
    const float* __restrict__ g,  const float* __restrict__ b,
    const int* __restrict__ out_idx, const int* __restrict__ in_idx,
    const float* __restrict__ qw, int E,
    float* __restrict__ q_pl, float* __restrict__ k_pl, float* __restrict__ v_pl,
    int* __restrict__ row_start, int4* __restrict__ meta,
    float4* __restrict__ zbase)
{
    const int lane = threadIdx.x;
    const int tile = blockIdx.x;
    const int grp  = blockIdx.y;

    if (grp >= 25) {                       // zero num+den: 68*NSEG floats
        const int n4 = (68 * NSEG) / 4;
        for (int i = ((grp - 25) * 115 + tile) * 64 + lane; i < n4; i += 2 * 115 * 64)
            zbase[i] = make_float4(0.f, 0.f, 0.f, 0.f);
        return;
    }
    if (grp == 24) {                       // meta + row_start build
        for (int e = tile * 64 + lane; e < E; e += 115 * 64) {
            int ho = out_idx[e * NLON] / NLON;
            if (e == 0) {
                row_start[ho] = 0;
            } else {
                int hp = out_idx[(e - 1) * NLON] / NLON;
                if (hp != ho) row_start[ho] = e;
            }
            if (e == E - 1) row_start[ho + 1] = E;
            int i0 = in_idx[e * NLON];     // wo = 0 column: hi*120 + dl
            int hi = i0 / NLON;
            int dl = i0 - hi * NLON;
            meta[e] = make_int4(hi * NLON, dl, __float_as_int(qw[i0]), ho);
        }
        return;
    }

    const int n = tile * 64 + lane;
    if (n >= NSEG) return;

    float xv[64];
    float s = 0.f, s2 = 0.f;
#pragma unroll
    for (int c = 0; c < 64; ++c) { float t = x[c * NSEG + n]; xv[c] = t; s += t; s2 += t * t; }
    float mean = s * 0.015625f;
    float var  = s2 * 0.015625f - mean * mean;
    float rstd = rsqrtf(var + 1e-6f);
#pragma unroll
    for (int c = 0; c < 64; ++c) xv[c] = (xv[c] - mean) * rstd * g[c] + b[c];

    const int mm    = grp >> 3;            // 0=q 1=k 2=v
    const int obase = (grp & 7) * 8;
    const float* __restrict__ w = (mm == 0) ? wq : (mm == 1) ? wk : wv;
    float* __restrict__ dst = (mm == 0) ? q_pl : (mm == 1) ? k_pl : v_pl;
    const float scale = (mm == 0) ? 0.25f : 1.0f;

#pragma unroll
    for (int j = 0; j < 8; ++j) {
        int o = obase + j;
        float acc = 0.f;
#pragma unroll
        for (int c = 0; c < 64; ++c) acc += w[o * 64 + c] * xv[c];
        dst[o * NSEG + n] = acc * scale;
    }
}

// ---------------------------------------------------------------------------
// K2: fused scores + PV. Block (row ho, 16-entry chunk), 128 thr, lane = wo.
// Entirely per-lane: score = dot over c of planar q/k (coalesced across
// lanes), alpha = exp(s)*qw, acc[c] += alpha*v[c][in]. No LDS, no shuffles,
// no barriers. qreg[64] hoisted per block. Epilogue: 64 num + 4 den
// atomicAdds per lane (distinct (c,seg) mostly; ~chunks/row contenders).
// No-max softmax (scores O(+-8); exp cannot overflow — R2..R6 validated).
// ---------------------------------------------------------------------------
__global__ __launch_bounds__(128) void k2_attn(
    const float* __restrict__ q_pl, const float* __restrict__ k_pl,
    const float* __restrict__ v_pl,
    const int4* __restrict__ meta,  const int* __restrict__ row_start,
    float* __restrict__ num, float* __restrict__ den)
{
    const int wo  = threadIdx.x;           // 0..127
    const bool aw = wo < NLON;
    const int woc = aw ? wo : (NLON - 1);
    const int ho  = blockIdx.x;

    int e0 = __builtin_amdgcn_readfirstlane(row_start[ho]);
    int e1 = __builtin_amdgcn_readfirstlane(row_start[ho + 1]);
    int eb = e0 + blockIdx.y * ECH;
    if (eb >= e1) return;
    int ee = eb + ECH; if (ee > e1) ee = e1;

    const int segc = ho * NLON + woc;
    float qreg[64];
#pragma unroll
    for (int c = 0; c < 64; ++c) qreg[c] = q_pl[c * NSEG + segc];

    float acc[64];
#pragma unroll
    for (int c = 0; c < 64; ++c) acc[c] = 0.f;
    float dh0 = 0.f, dh1 = 0.f, dh2 = 0.f, dh3 = 0.f;

    for (int e = eb; e < ee; ++e) {
        int4 mt = meta[e];
        int dlw = mt.y + woc; if (dlw >= NLON) dlw -= NLON;
        const float* __restrict__ kp = k_pl + (mt.x + dlw);
        const float* __restrict__ vp = v_pl + (mt.x + dlw);

        float s0 = 0.f, s1 = 0.f, s2 = 0.f, s3 = 0.f;
#pragma unroll
        for (int c = 0; c < 16; ++c) s0 += qreg[c]      * kp[c * NSEG];
#pragma unroll
        for (int c = 0; c < 16; ++c) s1 += qreg[16 + c] * kp[(16 + c) * NSEG];
#pragma unroll
        for (int c = 0; c < 16; ++c) s2 += qreg[32 + c] * kp[(32 + c) * NSEG];
#pragma unroll
        for (int c = 0; c < 16; ++c) s3 += qreg[48 + c] * kp[(48 + c) * NSEG];

        float qwv = aw ? __int_as_float(mt.z) : 0.f;
        float a0 = __expf(s0) * qwv, a1 = __expf(s1) * qwv;
        float a2 = __expf(s2) * qwv, a3 = __expf(s3) * qwv;
        dh0 += a0; dh1 += a1; dh2 += a2; dh3 += a3;

#pragma unroll
        for (int c = 0; c < 16; ++c) acc[c]      = fmaf(a0, vp[c * NSEG],        acc[c]);
#pragma unroll
        for (int c = 0; c < 16; ++c) acc[16 + c] = fmaf(a1, vp[(16 + c) * NSEG], acc[16 + c]);
#pragma unroll
        for (int c = 0; c < 16; ++c) acc[32 + c] = fmaf(a2, vp[(32 + c) * NSEG], acc[32 + c]);
#pragma unroll
        for (int c = 0; c < 16; ++c) acc[48 + c] = fmaf(a3, vp[(48 + c) * NSEG], acc[48 + c]);
    }

    if (aw) {
        const int seg = ho * NLON + wo;
#pragma unroll
        for (int c = 0; c < 64; ++c) atomicAdd(&num[c * NSEG + seg], acc[c]);
        atomicAdd(&den[0 * NSEG + seg], dh0);
        atomicAdd(&den[1 * NSEG + seg], dh1);
        atomicAdd(&den[2 * NSEG + seg], dh2);
        atomicAdd(&den[3 * NSEG + seg], dh3);
    }
}

// ---------------------------------------------------------------------------
// K2c: att = num/den, Wo projection + residual -> x1 planar.
// grid (115, 8): 8 output channels per group; thread-per-point, all planar.
// ---------------------------------------------------------------------------
__global__ __launch_bounds__(64) void k2c_wo(
    const float* __restrict__ num, const float* __restrict__ den,
    const float* __restrict__ wo,  const float* __restrict__ x,
    float* __restrict__ x1)
{
    const int lane = threadIdx.x;
    const int n    = blockIdx.x * 64 + lane;
    if (n >= NSEG) return;

    float rdh[4];
#pragma unroll
    for (int h = 0; h < 4; ++h) rdh[h] = 1.0f / den[h * NSEG + n];

    float att[64];
#pragma unroll
    for (int c = 0; c < 64; ++c) att[c] = num[c * NSEG + n] * rdh[c >> 4];

    const int o0 = blockIdx.y * 8;
#pragma unroll
    for (int j = 0; j < 8; ++j) {
        int o = o0 + j;
        float acc = 0.f;
#pragma unroll
        for (int c = 0; c < 64; ++c) acc += wo[o * 64 + c] * att[c];
        x1[o * NSEG + n] = acc + x[o * NSEG + n];
    }
}

// ---------------------------------------------------------------------------
// K3a: LayerNorm1 + W1 + exact gelu -> m_act planar [128][NSEG].
// grid (115, 16): 8 hidden units per group (1840 waves for latency hiding).
// ---------------------------------------------------------------------------
__global__ __launch_bounds__(64) void k3a_mlp1(
    const float* __restrict__ x1, const float* __restrict__ w1,
    const float* __restrict__ b1, const float* __restrict__ g,
    const float* __restrict__ bb, float* __restrict__ m_act)
{
    const int lane = threadIdx.x;
    const int n    = blockIdx.x * 64 + lane;
    if (n >= NSEG) return;

    float xv[64];
    float s = 0.f, s2 = 0.f;
#pragma unroll
    for (int c = 0; c < 64; ++c) { float t = x1[c * NSEG + n]; xv[c] = t; s += t; s2 += t * t; }
    float mean = s * 0.015625f;
    float var  = s2 * 0.015625f - mean * mean;
    float rstd = rsqrtf(var + 1e-6f);
#pragma unroll
    for (int c = 0; c < 64; ++c) xv[c] = (xv[c] - mean) * rstd * g[c] + bb[c];

    const int h0 = blockIdx.y * 8;
#pragma unroll
    for (int j = 0; j < 8; ++j) {
        int h = h0 + j;
        float mh = b1[h];
#pragma unroll
        for (int c = 0; c < 64; ++c) mh += w1[h * 64 + c] * xv[c];
        m_act[h * NSEG + n] = 0.5f * mh * (1.0f + erff(mh * 0.70710678118654752f));
    }
}

// ---------------------------------------------------------------------------
// K3b: out = W2 * m_act + b2 + x1. grid (115, 8): 8 output channels/group.
// ---------------------------------------------------------------------------
__global__ __launch_bounds__(64) void k3b_mlp2(
    const float* __restrict__ m_act, const float* __restrict__ w2,
    const float* __restrict__ b2,    const float* __restrict__ x1,
    float* __restrict__ out)
{
    const int lane = threadIdx.x;
    const int n    = blockIdx.x * 64 + lane;
    if (n >= NSEG) return;
    const int c0   = blockIdx.y * 8;

    float acc[8];
#pragma unroll
    for (int j = 0; j < 8; ++j) acc[j] = 0.f;

#pragma unroll 8
    for (int h = 0; h < HIDN; ++h) {
        float mh = m_act[h * NSEG + n];
#pragma unroll
        for (int j = 0; j < 8; ++j) acc[j] += w2[(c0 + j) * HIDN + h] * mh;
    }
#pragma unroll
    for (int j = 0; j < 8; ++j) {
        int c = c0 + j;
        out[c * NSEG + n] = acc[j] + b2[c] + x1[c * NSEG + n];
    }
}

// ---------------------------------------------------------------------------
extern "C" void kernel_launch(void* const* d_in, const int* in_sizes, int n_in,
                              void* d_out, int out_size, void* d_ws, size_t ws_size,
                              hipStream_t stream)
{
    const float* x    = (const float*)d_in[0];
    const float* wq   = (const float*)d_in[1];
    const float* wk   = (const float*)d_in[2];
    const float* wv   = (const float*)d_in[3];
    const float* wo   = (const float*)d_in[4];
    const float* w1   = (const float*)d_in[5];
    const float* b1   = (const float*)d_in[6];
    const float* w2   = (const float*)d_in[7];
    const float* b2   = (const float*)d_in[8];
    const float* ln0g = (const float*)d_in[9];
    const float* ln0b = (const float*)d_in[10];
    const float* ln1g = (const float*)d_in[11];
    const float* ln1b = (const float*)d_in[12];
    const float* qw   = (const float*)d_in[13];
    const int* out_idx = (const int*)d_in[14];
    const int* in_idx  = (const int*)d_in[15];
    float* out = (float*)d_out;

    const int NNZ = in_sizes[15];
    const int E   = NNZ / NLON;
    const size_t N64 = (size_t)NSEG * 64;

    float* ws    = (float*)d_ws;
    float* q_pl  = ws;                     // [64][NSEG]
    float* k_pl  = ws + N64;
    float* v_pl  = ws + 2 * N64;
    float* num   = ws + 3 * N64;           // [64][NSEG]  (zeroed by k1)
    float* den   = ws + 4 * N64;           // [4][NSEG]   (zeroed, contiguous w/ num)
    float* x1    = ws + 4 * N64 + 4 * NSEG;
    float* m_act = ws + 5 * N64 + 4 * NSEG;           // [128][NSEG]
    int*   row_start = (int*)(ws + 7 * N64 + 4 * NSEG);            // [62]
    int4*  meta  = (int4*)(ws + 7 * N64 + 4 * NSEG + 64);          // [E]

    hipLaunchKernelGGL(k1_ln_qkv, dim3(115, 27), dim3(64), 0, stream,
                       x, wq, wk, wv, ln0g, ln0b, out_idx, in_idx, qw, E,
                       q_pl, k_pl, v_pl, row_start, meta, (float4*)num);
    hipLaunchKernelGGL(k2_attn, dim3(61, MAXCH), dim3(128), 0, stream,
                       q_pl, k_pl, v_pl, meta, row_start, num, den);
    hipLaunchKernelGGL(k2c_wo, dim3(115, 8), dim3(64), 0, stream,
                       num, den, wo, x, x1);
    hipLaunchKernelGGL(k3a_mlp1, dim3(115, 16), dim3(64), 0, stream,
                       x1, w1, b1, ln1g, ln1b, m_act);
    hipLaunchKernelGGL(k3b_mlp2, dim3(115, 8), dim3(64), 0, stream,
                       m_act, w2, b2, x1, out);
}

// Round 8
// 306.312 us; speedup vs baseline: 1.0037x; 1.0037x over previous
//
#include <hip/hip_runtime.h>
#include <math.h>

#define NSEG 7320
#define NLON 120
#define HIDN 128
#define ECH  16     // entries per k2 block (uniform -> perfect balance)
#define MAXCH 48    // 48*16 = 768-entry cap per row (max row ~520; R4/R6-proven)

// ---------------------------------------------------------------------------
// K1: grp 0-23: LN0 + QKV projection (8 output channels per group), planar
// [64][NSEG] outputs, coalesced. q pre-scaled by 1/sqrt(DH)=0.25.
// grp 24: meta {hi*120, dl, qw bits, ho} + per-lat-row CSR offsets.
// grp 25-26: zero num[64][NSEG]+den[4][NSEG] (contiguous, float4 stride loop).
// ---------------------------------------------------------------------------
__global__ __launch_bounds__(64) void k1_ln_qkv(
    const float* __restrict__ x,  const float* __restrict__ wq,
    const float* __restrict__ wk, const float* __restrict__ wv,
    const float* __restrict__ g,  const float* __restrict__ b,
    const int* __restrict__ out_idx, const int* __restrict__ in_idx,
    const float* __restrict__ qw, int E,
    float* __restrict__ q_pl, float* __restrict__ k_pl, float* __restrict__ v_pl,
    int* __restrict__ row_start, int4* __restrict__ meta,
    float4* __restrict__ zbase)
{
    const int lane = threadIdx.x;
    const int tile = blockIdx.x;
    const int grp  = blockIdx.y;

    if (grp >= 25) {                       // zero num+den: 68*NSEG floats
        const int n4 = (68 * NSEG) / 4;
        for (int i = ((grp - 25) * 115 + tile) * 64 + lane; i < n4; i += 2 * 115 * 64)
            zbase[i] = make_float4(0.f, 0.f, 0.f, 0.f);
        return;
    }
    if (grp == 24) {                       // meta + row_start build
        for (int e = tile * 64 + lane; e < E; e += 115 * 64) {
            int ho = out_idx[e * NLON] / NLON;
            if (e == 0) {
                row_start[ho] = 0;
            } else {
                int hp = out_idx[(e - 1) * NLON] / NLON;
                if (hp != ho) row_start[ho] = e;
            }
            if (e == E - 1) row_start[ho + 1] = E;
            int i0 = in_idx[e * NLON];     // wo = 0 column: hi*120 + dl
            int hi = i0 / NLON;
            int dl = i0 - hi * NLON;
            meta[e] = make_int4(hi * NLON, dl, __float_as_int(qw[i0]), ho);
        }
        return;
    }

    const int n = tile * 64 + lane;
    if (n >= NSEG) return;

    float xv[64];
    float s = 0.f, s2 = 0.f;
#pragma unroll
    for (int c = 0; c < 64; ++c) { float t = x[c * NSEG + n]; xv[c] = t; s += t; s2 += t * t; }
    float mean = s * 0.015625f;
    float var  = s2 * 0.015625f - mean * mean;
    float rstd = rsqrtf(var + 1e-6f);
#pragma unroll
    for (int c = 0; c < 64; ++c) xv[c] = (xv[c] - mean) * rstd * g[c] + b[c];

    const int mm    = grp >> 3;            // 0=q 1=k 2=v
    const int obase = (grp & 7) * 8;
    const float* __restrict__ w = (mm == 0) ? wq : (mm == 1) ? wk : wv;
    float* __restrict__ dst = (mm == 0) ? q_pl : (mm == 1) ? k_pl : v_pl;
    const float scale = (mm == 0) ? 0.25f : 1.0f;

#pragma unroll
    for (int j = 0; j < 8; ++j) {
        int o = obase + j;
        float acc = 0.f;
#pragma unroll
        for (int c = 0; c < 64; ++c) acc += w[o * 64 + c] * xv[c];
        dst[o * NSEG + n] = acc * scale;
    }
}

// ---------------------------------------------------------------------------
// K2: fused scores + PV. Block (row ho, 16-entry chunk), 128 thr, lane = wo.
// Entirely per-lane: score = dot over c of planar q/k (coalesced across
// lanes), alpha = exp(s)*qw, acc[c] += alpha*v[c][in]. No LDS, no shuffles,
// no barriers. qreg[64] hoisted per block. Epilogue: 64 num + 4 den
// atomicAdds per lane. No-max softmax (scores O(+-8); R2..R7 validated).
// __launch_bounds__(128, 1): min 1 wave/EU -> VGPR cap ~512 so qreg[64]+
// acc[64] stay in registers (R7's default heuristic capped at 80 VGPRs and
// spilled the accumulators to scratch: 17.5 MB writes, 170 us).
// ---------------------------------------------------------------------------
__global__ __launch_bounds__(128, 1) void k2_attn(
    const float* __restrict__ q_pl, const float* __restrict__ k_pl,
    const float* __restrict__ v_pl,
    const int4* __restrict__ meta,  const int* __restrict__ row_start,
    float* __restrict__ num, float* __restrict__ den)
{
    const int wo  = threadIdx.x;           // 0..127
    const bool aw = wo < NLON;
    const int woc = aw ? wo : (NLON - 1);
    const int ho  = blockIdx.x;

    int e0 = __builtin_amdgcn_readfirstlane(row_start[ho]);
    int e1 = __builtin_amdgcn_readfirstlane(row_start[ho + 1]);
    int eb = e0 + blockIdx.y * ECH;
    if (eb >= e1) return;
    int ee = eb + ECH; if (ee > e1) ee = e1;

    const int segc = ho * NLON + woc;
    float qreg[64];
#pragma unroll
    for (int c = 0; c < 64; ++c) qreg[c] = q_pl[c * NSEG + segc];

    float acc[64];
#pragma unroll
    for (int c = 0; c < 64; ++c) acc[c] = 0.f;
    float dh0 = 0.f, dh1 = 0.f, dh2 = 0.f, dh3 = 0.f;

    for (int e = eb; e < ee; ++e) {
        int4 mt = meta[e];
        int dlw = mt.y + woc; if (dlw >= NLON) dlw -= NLON;
        const float* __restrict__ kp = k_pl + (mt.x + dlw);
        const float* __restrict__ vp = v_pl + (mt.x + dlw);

        float s0 = 0.f, s1 = 0.f, s2 = 0.f, s3 = 0.f;
#pragma unroll
        for (int c = 0; c < 16; ++c) s0 += qreg[c]      * kp[c * NSEG];
#pragma unroll
        for (int c = 0; c < 16; ++c) s1 += qreg[16 + c] * kp[(16 + c) * NSEG];
#pragma unroll
        for (int c = 0; c < 16; ++c) s2 += qreg[32 + c] * kp[(32 + c) * NSEG];
#pragma unroll
        for (int c = 0; c < 16; ++c) s3 += qreg[48 + c] * kp[(48 + c) * NSEG];

        float qwv = aw ? __int_as_float(mt.z) : 0.f;
        float a0 = __expf(s0) * qwv, a1 = __expf(s1) * qwv;
        float a2 = __expf(s2) * qwv, a3 = __expf(s3) * qwv;
        dh0 += a0; dh1 += a1; dh2 += a2; dh3 += a3;

#pragma unroll
        for (int c = 0; c < 16; ++c) acc[c]      = fmaf(a0, vp[c * NSEG],        acc[c]);
#pragma unroll
        for (int c = 0; c < 16; ++c) acc[16 + c] = fmaf(a1, vp[(16 + c) * NSEG], acc[16 + c]);
#pragma unroll
        for (int c = 0; c < 16; ++c) acc[32 + c] = fmaf(a2, vp[(32 + c) * NSEG], acc[32 + c]);
#pragma unroll
        for (int c = 0; c < 16; ++c) acc[48 + c] = fmaf(a3, vp[(48 + c) * NSEG], acc[48 + c]);
    }

    if (aw) {
        const int seg = ho * NLON + wo;
#pragma unroll
        for (int c = 0; c < 64; ++c) atomicAdd(&num[c * NSEG + seg], acc[c]);
        atomicAdd(&den[0 * NSEG + seg], dh0);
        atomicAdd(&den[1 * NSEG + seg], dh1);
        atomicAdd(&den[2 * NSEG + seg], dh2);
        atomicAdd(&den[3 * NSEG + seg], dh3);
    }
}

// ---------------------------------------------------------------------------
// K2c: att = num/den, Wo projection + residual -> x1 planar.
// grid (115, 8): 8 output channels per group; thread-per-point, all planar.
// ---------------------------------------------------------------------------
__global__ __launch_bounds__(64) void k2c_wo(
    const float* __restrict__ num, const float* __restrict__ den,
    const float* __restrict__ wo,  const float* __restrict__ x,
    float* __restrict__ x1)
{
    const int lane = threadIdx.x;
    const int n    = blockIdx.x * 64 + lane;
    if (n >= NSEG) return;

    float rdh[4];
#pragma unroll
    for (int h = 0; h < 4; ++h) rdh[h] = 1.0f / den[h * NSEG + n];

    float att[64];
#pragma unroll
    for (int c = 0; c < 64; ++c) att[c] = num[c * NSEG + n] * rdh[c >> 4];

    const int o0 = blockIdx.y * 8;
#pragma unroll
    for (int j = 0; j < 8; ++j) {
        int o = o0 + j;
        float acc = 0.f;
#pragma unroll
        for (int c = 0; c < 64; ++c) acc += wo[o * 64 + c] * att[c];
        x1[o * NSEG + n] = acc + x[o * NSEG + n];
    }
}

// ---------------------------------------------------------------------------
// K3a: LayerNorm1 + W1 + exact gelu -> m_act planar [128][NSEG].
// grid (115, 16): 8 hidden units per group (1840 waves for latency hiding).
// ---------------------------------------------------------------------------
__global__ __launch_bounds__(64) void k3a_mlp1(
    const float* __restrict__ x1, const float* __restrict__ w1,
    const float* __restrict__ b1, const float* __restrict__ g,
    const float* __restrict__ bb, float* __restrict__ m_act)
{
    const int lane = threadIdx.x;
    const int n    = blockIdx.x * 64 + lane;
    if (n >= NSEG) return;

    float xv[64];
    float s = 0.f, s2 = 0.f;
#pragma unroll
    for (int c = 0; c < 64; ++c) { float t = x1[c * NSEG + n]; xv[c] = t; s += t; s2 += t * t; }
    float mean = s * 0.015625f;
    float var  = s2 * 0.015625f - mean * mean;
    float rstd = rsqrtf(var + 1e-6f);
#pragma unroll
    for (int c = 0; c < 64; ++c) xv[c] = (xv[c] - mean) * rstd * g[c] + bb[c];

    const int h0 = blockIdx.y * 8;
#pragma unroll
    for (int j = 0; j < 8; ++j) {
        int h = h0 + j;
        float mh = b1[h];
#pragma unroll
        for (int c = 0; c < 64; ++c) mh += w1[h * 64 + c] * xv[c];
        m_act[h * NSEG + n] = 0.5f * mh * (1.0f + erff(mh * 0.70710678118654752f));
    }
}

// ---------------------------------------------------------------------------
// K3b: out = W2 * m_act + b2 + x1. grid (115, 8): 8 output channels/group.
// ---------------------------------------------------------------------------
__global__ __launch_bounds__(64) void k3b_mlp2(
    const float* __restrict__ m_act, const float* __restrict__ w2,
    const float* __restrict__ b2,    const float* __restrict__ x1,
    float* __restrict__ out)
{
    const int lane = threadIdx.x;
    const int n    = blockIdx.x * 64 + lane;
    if (n >= NSEG) return;
    const int c0   = blockIdx.y * 8;

    float acc[8];
#pragma unroll
    for (int j = 0; j < 8; ++j) acc[j] = 0.f;

#pragma unroll 8
    for (int h = 0; h < HIDN; ++h) {
        float mh = m_act[h * NSEG + n];
#pragma unroll
        for (int j = 0; j < 8; ++j) acc[j] += w2[(c0 + j) * HIDN + h] * mh;
    }
#pragma unroll
    for (int j = 0; j < 8; ++j) {
        int c = c0 + j;
        out[c * NSEG + n] = acc[j] + b2[c] + x1[c * NSEG + n];
    }
}

// ---------------------------------------------------------------------------
extern "C" void kernel_launch(void* const* d_in, const int* in_sizes, int n_in,
                              void* d_out, int out_size, void* d_ws, size_t ws_size,
                              hipStream_t stream)
{
    const float* x    = (const float*)d_in[0];
    const float* wq   = (const float*)d_in[1];
    const float* wk   = (const float*)d_in[2];
    const float* wv   = (const float*)d_in[3];
    const float* wo   = (const float*)d_in[4];
    const float* w1   = (const float*)d_in[5];
    const float* b1   = (const float*)d_in[6];
    const float* w2   = (const float*)d_in[7];
    const float* b2   = (const float*)d_in[8];
    const float* ln0g = (const float*)d_in[9];
    const float* ln0b = (const float*)d_in[10];
    const float* ln1g = (const float*)d_in[11];
    const float* ln1b = (const float*)d_in[12];
    const float* qw   = (const float*)d_in[13];
    const int* out_idx = (const int*)d_in[14];
    const int* in_idx  = (const int*)d_in[15];
    float* out = (float*)d_out;

    const int NNZ = in_sizes[15];
    const int E   = NNZ / NLON;
    const size_t N64 = (size_t)NSEG * 64;

    float* ws    = (float*)d_ws;
    float* q_pl  = ws;                     // [64][NSEG]
    float* k_pl  = ws + N64;
    float* v_pl  = ws + 2 * N64;
    float* num   = ws + 3 * N64;           // [64][NSEG]  (zeroed by k1)
    float* den   = ws + 4 * N64;           // [4][NSEG]   (zeroed, contiguous w/ num)
    float* x1    = ws + 4 * N64 + 4 * NSEG;
    float* m_act = ws + 5 * N64 + 4 * NSEG;           // [128][NSEG]
    int*   row_start = (int*)(ws + 7 * N64 + 4 * NSEG);            // [62]
    int4*  meta  = (int4*)(ws + 7 * N64 + 4 * NSEG + 64);          // [E]

    hipLaunchKernelGGL(k1_ln_qkv, dim3(115, 27), dim3(64), 0, stream,
                       x, wq, wk, wv, ln0g, ln0b, out_idx, in_idx, qw, E,
                       q_pl, k_pl, v_pl, row_start, meta, (float4*)num);
    hipLaunchKernelGGL(k2_attn, dim3(61, MAXCH), dim3(128), 0, stream,
                       q_pl, k_pl, v_pl, meta, row_start, num, den);
    hipLaunchKernelGGL(k2c_wo, dim3(115, 8), dim3(64), 0, stream,
                       num, den, wo, x, x1);
    hipLaunchKernelGGL(k3a_mlp1, dim3(115, 16), dim3(64), 0, stream,
                       x1, w1, b1, ln1g, ln1b, m_act);
    hipLaunchKernelGGL(k3b_mlp2, dim3(115, 8), dim3(64), 0, stream,
                       m_act, w2, b2, x1, out);
}

// Round 9
// 186.821 us; speedup vs baseline: 1.6456x; 1.6396x over previous
//
#include <hip/hip_runtime.h>
#include <math.h>

#define NSEG 7320
#define NLON 120
#define HIDN 128
#define ECH  16     // entries per k2 block chunk
#define MAXCH 48    // 48*16 = 768-entry cap per row (max row ~520; R4/R6-proven)

// ---------------------------------------------------------------------------
// K1: grp 0-23: LN0 + QKV projection (8 output channels per group), planar
// [64][NSEG] outputs, coalesced. q pre-scaled by 1/sqrt(DH)=0.25.
// grp 24: meta {hi*120, dl, qw bits, ho} + per-lat-row CSR offsets.
// grp 25-26: zero num[64][NSEG]+den[4][NSEG] (contiguous, float4 stride loop).
// ---------------------------------------------------------------------------
__global__ __launch_bounds__(64) void k1_ln_qkv(
    const float* __restrict__ x,  const float* __restrict__ wq,
    const float* __restrict__ wk, const float* __restrict__ wv,
    const float* __restrict__ g,  const float* __restrict__ b,
    const int* __restrict__ out_idx, const int* __restrict__ in_idx,
    const float* __restrict__ qw, int E,
    float* __restrict__ q_pl, float* __restrict__ k_pl, float* __restrict__ v_pl,
    int* __restrict__ row_start, int4* __restrict__ meta,
    float4* __restrict__ zbase)
{
    const int lane = threadIdx.x;
    const int tile = blockIdx.x;
    const int grp  = blockIdx.y;

    if (grp >= 25) {                       // zero num+den: 68*NSEG floats
        const int n4 = (68 * NSEG) / 4;
        for (int i = ((grp - 25) * 115 + tile) * 64 + lane; i < n4; i += 2 * 115 * 64)
            zbase[i] = make_float4(0.f, 0.f, 0.f, 0.f);
        return;
    }
    if (grp == 24) {                       // meta + row_start build
        for (int e = tile * 64 + lane; e < E; e += 115 * 64) {
            int ho = out_idx[e * NLON] / NLON;
            if (e == 0) {
                row_start[ho] = 0;
            } else {
                int hp = out_idx[(e - 1) * NLON] / NLON;
                if (hp != ho) row_start[ho] = e;
            }
            if (e == E - 1) row_start[ho + 1] = E;
            int i0 = in_idx[e * NLON];     // wo = 0 column: hi*120 + dl
            int hi = i0 / NLON;
            int dl = i0 - hi * NLON;
            meta[e] = make_int4(hi * NLON, dl, __float_as_int(qw[i0]), ho);
        }
        return;
    }

    const int n = tile * 64 + lane;
    if (n >= NSEG) return;

    float xv[64];
    float s = 0.f, s2 = 0.f;
#pragma unroll
    for (int c = 0; c < 64; ++c) { float t = x[c * NSEG + n]; xv[c] = t; s += t; s2 += t * t; }
    float mean = s * 0.015625f;
    float var  = s2 * 0.015625f - mean * mean;
    float rstd = rsqrtf(var + 1e-6f);
#pragma unroll
    for (int c = 0; c < 64; ++c) xv[c] = (xv[c] - mean) * rstd * g[c] + b[c];

    const int mm    = grp >> 3;            // 0=q 1=k 2=v
    const int obase = (grp & 7) * 8;
    const float* __restrict__ w = (mm == 0) ? wq : (mm == 1) ? wk : wv;
    float* __restrict__ dst = (mm == 0) ? q_pl : (mm == 1) ? k_pl : v_pl;
    const float scale = (mm == 0) ? 0.25f : 1.0f;

#pragma unroll
    for (int j = 0; j < 8; ++j) {
        int o = obase + j;
        float acc = 0.f;
#pragma unroll
        for (int c = 0; c < 64; ++c) acc += w[o * 64 + c] * xv[c];
        dst[o * NSEG + n] = acc * scale;
    }
}

// ---------------------------------------------------------------------------
// K2: fused scores + PV, one HEAD per block. Block (row ho, 16-entry chunk,
// head), 128 thr, lane = wo. Per-lane only: score = 16-ch dot of planar q/k
// (coalesced across lanes), alpha = exp(s)*qw, acc[16] += alpha*v. qreg[16]+
// acc[16] ~ 50 VGPRs — fits default allocator (R7/R8: the 64-ch version was
// capped at 80 VGPRs, spilling qreg[64] to scratch -> 17.5 MB writes,
// batch-serialized loads, 170 us). Epilogue: 16 num + 1 den atomics/lane.
// No-max softmax (scores O(+-8); R2..R8 validated).
// ---------------------------------------------------------------------------
__global__ __launch_bounds__(128) void k2_attn(
    const float* __restrict__ q_pl, const float* __restrict__ k_pl,
    const float* __restrict__ v_pl,
    const int4* __restrict__ meta,  const int* __restrict__ row_start,
    float* __restrict__ num, float* __restrict__ den)
{
    const int wo  = threadIdx.x;           // 0..127
    const bool aw = wo < NLON;
    const int woc = aw ? wo : (NLON - 1);
    const int ho  = blockIdx.x;
    const int head = blockIdx.z;           // 0..3
    const int cb  = head * 16;

    int e0 = __builtin_amdgcn_readfirstlane(row_start[ho]);
    int e1 = __builtin_amdgcn_readfirstlane(row_start[ho + 1]);
    int eb = e0 + blockIdx.y * ECH;
    if (eb >= e1) return;
    int ee = eb + ECH; if (ee > e1) ee = e1;

    const int segc = ho * NLON + woc;
    const float* __restrict__ qb = q_pl + (size_t)cb * NSEG;
    const float* __restrict__ kb = k_pl + (size_t)cb * NSEG;
    const float* __restrict__ vb = v_pl + (size_t)cb * NSEG;

    float qreg[16];
#pragma unroll
    for (int c = 0; c < 16; ++c) qreg[c] = qb[c * NSEG + segc];

    float acc[16];
#pragma unroll
    for (int c = 0; c < 16; ++c) acc[c] = 0.f;
    float dh = 0.f;

#pragma unroll 2
    for (int e = eb; e < ee; ++e) {
        int4 mt = meta[e];
        int dlw = mt.y + woc; if (dlw >= NLON) dlw -= NLON;
        const float* __restrict__ kp = kb + (mt.x + dlw);
        const float* __restrict__ vp = vb + (mt.x + dlw);

        float sa = 0.f, sb = 0.f;
#pragma unroll
        for (int c = 0; c < 8; ++c)  sa += qreg[c]     * kp[c * NSEG];
#pragma unroll
        for (int c = 0; c < 8; ++c)  sb += qreg[8 + c] * kp[(8 + c) * NSEG];

        float qwv = aw ? __int_as_float(mt.z) : 0.f;
        float a = __expf(sa + sb) * qwv;
        dh += a;

#pragma unroll
        for (int c = 0; c < 16; ++c) acc[c] = fmaf(a, vp[c * NSEG], acc[c]);
    }

    if (aw) {
        const int seg = ho * NLON + wo;
#pragma unroll
        for (int c = 0; c < 16; ++c) atomicAdd(&num[(cb + c) * NSEG + seg], acc[c]);
        atomicAdd(&den[head * NSEG + seg], dh);
    }
}

// ---------------------------------------------------------------------------
// K2c: att = num/den, Wo projection + residual -> x1 planar.
// grid (115, 8): 8 output channels per group; thread-per-point, all planar.
// ---------------------------------------------------------------------------
__global__ __launch_bounds__(64) void k2c_wo(
    const float* __restrict__ num, const float* __restrict__ den,
    const float* __restrict__ wo,  const float* __restrict__ x,
    float* __restrict__ x1)
{
    const int lane = threadIdx.x;
    const int n    = blockIdx.x * 64 + lane;
    if (n >= NSEG) return;

    float rdh[4];
#pragma unroll
    for (int h = 0; h < 4; ++h) rdh[h] = 1.0f / den[h * NSEG + n];

    float att[64];
#pragma unroll
    for (int c = 0; c < 64; ++c) att[c] = num[c * NSEG + n] * rdh[c >> 4];

    const int o0 = blockIdx.y * 8;
#pragma unroll
    for (int j = 0; j < 8; ++j) {
        int o = o0 + j;
        float acc = 0.f;
#pragma unroll
        for (int c = 0; c < 64; ++c) acc += wo[o * 64 + c] * att[c];
        x1[o * NSEG + n] = acc + x[o * NSEG + n];
    }
}

// ---------------------------------------------------------------------------
// K3a: LayerNorm1 + W1 + exact gelu -> m_act planar [128][NSEG].
// grid (115, 16): 8 hidden units per group (1840 waves for latency hiding).
// ---------------------------------------------------------------------------
__global__ __launch_bounds__(64) void k3a_mlp1(
    const float* __restrict__ x1, const float* __restrict__ w1,
    const float* __restrict__ b1, const float* __restrict__ g,
    const float* __restrict__ bb, float* __restrict__ m_act)
{
    const int lane = threadIdx.x;
    const int n    = blockIdx.x * 64 + lane;
    if (n >= NSEG) return;

    float xv[64];
    float s = 0.f, s2 = 0.f;
#pragma unroll
    for (int c = 0; c < 64; ++c) { float t = x1[c * NSEG + n]; xv[c] = t; s += t; s2 += t * t; }
    float mean = s * 0.015625f;
    float var  = s2 * 0.015625f - mean * mean;
    float rstd = rsqrtf(var + 1e-6f);
#pragma unroll
    for (int c = 0; c < 64; ++c) xv[c] = (xv[c] - mean) * rstd * g[c] + bb[c];

    const int h0 = blockIdx.y * 8;
#pragma unroll
    for (int j = 0; j < 8; ++j) {
        int h = h0 + j;
        float mh = b1[h];
#pragma unroll
        for (int c = 0; c < 64; ++c) mh += w1[h * 64 + c] * xv[c];
        m_act[h * NSEG + n] = 0.5f * mh * (1.0f + erff(mh * 0.70710678118654752f));
    }
}

// ---------------------------------------------------------------------------
// K3b: out = W2 * m_act + b2 + x1. grid (115, 8): 8 output channels/group.
// ---------------------------------------------------------------------------
__global__ __launch_bounds__(64) void k3b_mlp2(
    const float* __restrict__ m_act, const float* __restrict__ w2,
    const float* __restrict__ b2,    const float* __restrict__ x1,
    float* __restrict__ out)
{
    const int lane = threadIdx.x;
    const int n    = blockIdx.x * 64 + lane;
    if (n >= NSEG) return;
    const int c0   = blockIdx.y * 8;

    float acc[8];
#pragma unroll
    for (int j = 0; j < 8; ++j) acc[j] = 0.f;

#pragma unroll 8
    for (int h = 0; h < HIDN; ++h) {
        float mh = m_act[h * NSEG + n];
#pragma unroll
        for (int j = 0; j < 8; ++j) acc[j] += w2[(c0 + j) * HIDN + h] * mh;
    }
#pragma unroll
    for (int j = 0; j < 8; ++j) {
        int c = c0 + j;
        out[c * NSEG + n] = acc[j] + b2[c] + x1[c * NSEG + n];
    }
}

// ---------------------------------------------------------------------------
extern "C" void kernel_launch(void* const* d_in, const int* in_sizes, int n_in,
                              void* d_out, int out_size, void* d_ws, size_t ws_size,
                              hipStream_t stream)
{
    const float* x    = (const float*)d_in[0];
    const float* wq   = (const float*)d_in[1];
    const float* wk   = (const float*)d_in[2];
    const float* wv   = (const float*)d_in[3];
    const float* wo   = (const float*)d_in[4];
    const float* w1   = (const float*)d_in[5];
    const float* b1   = (const float*)d_in[6];
    const float* w2   = (const float*)d_in[7];
    const float* b2   = (const float*)d_in[8];
    const float* ln0g = (const float*)d_in[9];
    const float* ln0b = (const float*)d_in[10];
    const float* ln1g = (const float*)d_in[11];
    const float* ln1b = (const float*)d_in[12];
    const float* qw   = (const float*)d_in[13];
    const int* out_idx = (const int*)d_in[14];
    const int* in_idx  = (const int*)d_in[15];
    float* out = (float*)d_out;

    const int NNZ = in_sizes[15];
    const int E   = NNZ / NLON;
    const size_t N64 = (size_t)NSEG * 64;

    float* ws    = (float*)d_ws;
    float* q_pl  = ws;                     // [64][NSEG]
    float* k_pl  = ws + N64;
    float* v_pl  = ws + 2 * N64;
    float* num   = ws + 3 * N64;           // [64][NSEG]  (zeroed by k1)
    float* den   = ws + 4 * N64;           // [4][NSEG]   (zeroed, contiguous w/ num)
    float* x1    = ws + 4 * N64 + 4 * NSEG;
    float* m_act = ws + 5 * N64 + 4 * NSEG;           // [128][NSEG]
    int*   row_start = (int*)(ws + 7 * N64 + 4 * NSEG);            // [62]
    int4*  meta  = (int4*)(ws + 7 * N64 + 4 * NSEG + 64);          // [E]

    hipLaunchKernelGGL(k1_ln_qkv, dim3(115, 27), dim3(64), 0, stream,
                       x, wq, wk, wv, ln0g, ln0b, out_idx, in_idx, qw, E,
                       q_pl, k_pl, v_pl, row_start, meta, (float4*)num);
    hipLaunchKernelGGL(k2_attn, dim3(61, MAXCH, 4), dim3(128), 0, stream,
                       q_pl, k_pl, v_pl, meta, row_start, num, den);
    hipLaunchKernelGGL(k2c_wo, dim3(115, 8), dim3(64), 0, stream,
                       num, den, wo, x, x1);
    hipLaunchKernelGGL(k3a_mlp1, dim3(115, 16), dim3(64), 0, stream,
                       x1, w1, b1, ln1g, ln1b, m_act);
    hipLaunchKernelGGL(k3b_mlp2, dim3(115, 8), dim3(64), 0, stream,
                       m_act, w2, b2, x1, out);
}